// Round 8
// baseline (126.779 us; speedup 1.0000x reference)
//
#include <hip/hip_runtime.h>

// NCC2D fused: 5 box-sums (9x9, zero-pad) + cc + global mean.
// R8: single-wave workgroups. R7 counters (main ~48us, HBM 12%, VALU 24%,
// Occ 20%) showed latency-bound: 47.6KB LDS -> only 3 blocks/CU, and 32
// four-wave barriers per block. New tiling: 1 wave (64 thr) owns a
// 128col x 16row tile; grid 4x32x32 = 4096 blocks -> ~12 blocks(waves)/CU
// resident (LDS 12.5KB). Workgroup == wave, so __syncthreads() compiles to
// a free wave-level fence: ZERO s_barrier cost. Lanes 0-7 each maintain one
// extra halo column (cols +-4 outside the 128-col core) so the horizontal
// 9-window needs no inter-block exchange. Input rows read once into a 9-row
// LDS ring (subtract row re-read from LDS, not global -- R7's fix, kept).
// d_ws: 4096 block partials (float). Kernel 2 reduces in double -> -mean.

#define BATCH     32
#define IMH       512
#define IMW       512
#define SH        16          // output rows per block
#define NROWSTRIP 32          // 512/16
#define NCOLSTRIP 4           // 512/128
#define CBW       128         // output cols per block
#define NPART     (BATCH * NROWSTRIP * NCOLSTRIP)   // 4096
#define NK        (SH + 8)    // input rows per block (24)
#define VROW      136         // 4 halo + 128 + 4 halo

// load current row: 2 core cols (float2) + 1 halo col on lanes 0..7
#define LOADROW(RI, CI, CJ, HI, HJ) do {                                   \
    const int ri_ = (RI);                                                  \
    CI = make_float2(0.f, 0.f); CJ = make_float2(0.f, 0.f);                \
    HI = 0.f; HJ = 0.f;                                                    \
    if ((unsigned)ri_ < (unsigned)IMH) {                                   \
        const float* rI_ = Ib + (size_t)ri_ * IMW;                         \
        const float* rJ_ = Jb + (size_t)ri_ * IMW;                         \
        CI = *(const float2*)(rI_ + cc0);                                  \
        CJ = *(const float2*)(rJ_ + cc0);                                  \
        if (u < 8 && (unsigned)hc < (unsigned)IMW) {                       \
            HI = rI_[hc]; HJ = rJ_[hc];                                    \
        }                                                                  \
    }                                                                      \
} while (0)

// horizontal 9-window sums for the 2 owned cols from Vbuf row QI
#define HWIN(QI, HA, HB) do {                                              \
    const float2 w0_ = *(const float2*)&Vbuf[QI][l0];                      \
    const float2 w1_ = *(const float2*)&Vbuf[QI][l0 + 2];                  \
    const float2 w2_ = *(const float2*)&Vbuf[QI][l0 + 4];                  \
    const float2 w3_ = *(const float2*)&Vbuf[QI][l0 + 6];                  \
    const float2 w4_ = *(const float2*)&Vbuf[QI][l0 + 8];                  \
    HA = ((w0_.x + w0_.y) + (w1_.x + w1_.y))                               \
       + ((w2_.x + w2_.y) + (w3_.x + w3_.y)) + w4_.x;                      \
    HB = HA + w4_.y - w0_.x;                                               \
} while (0)

#define CC1(AI, AJ, S2, S3, S4) do {                                       \
    const float cross = (S4) - (AI)*(AJ)*inv81;                            \
    const float ivv   = (S2) - (AI)*(AI)*inv81;                            \
    const float jvv   = (S3) - (AJ)*(AJ)*inv81;                            \
    acc += cross * cross * __builtin_amdgcn_rcpf(ivv * jvv + 1e-5f);       \
} while (0)

__global__ __launch_bounds__(64) void ncc_main(const float* __restrict__ I,
                                               const float* __restrict__ J,
                                               float* __restrict__ partial) {
    const int u    = threadIdx.x;        // 0..63
    const int cs   = blockIdx.x;         // col strip (0..3)
    const int s    = blockIdx.y;         // row strip (0..31)
    const int b    = blockIdx.z;         // image
    const int r0   = s * SH;
    const int cblk = cs * CBW;
    const int cc0  = cblk + 2 * u;       // first owned col (absolute)
    // halo col for lanes 0..7: lanes 0-3 -> cols cblk-4..cblk-1,
    // lanes 4-7 -> cols cblk+128..cblk+131 (OOB -> zeros via guard)
    const int hc   = cblk + (u < 4 ? u - 4 : 124 + u);
    const int hx   = (u < 4) ? u : 128 + u;   // Vbuf idx for halo col
    const int l0   = 2 * u;              // HWIN base idx for owned cols
    const float inv81 = 1.0f / 81.0f;

    const float* Ib = I + (size_t)b * IMH * IMW;
    const float* Jb = J + (size_t)b * IMH * IMW;

    __shared__ float4 ring[9][64];       // 9.2 KB: core cols (I0,I1,J0,J1)
    __shared__ float2 ringH[9][8];       // 576 B: halo col (I,J)
    __shared__ float  Vbuf[5][VROW];     // 2.7 KB exchange buffer

    float VI0 = 0.f, VI1 = 0.f, VJ0 = 0.f, VJ1 = 0.f;
    float VII0 = 0.f, VII1 = 0.f, VJJ0 = 0.f, VJJ1 = 0.f;
    float VIJ0 = 0.f, VIJ1 = 0.f;
    float hVI = 0.f, hVJ = 0.f, hVII = 0.f, hVJJ = 0.f, hVIJ = 0.f;
    float acc = 0.f;
    int slot = 0;

    // prefetch first input row (r0-4; OOB -> zeros)
    float2 ci, cj; float hi, hj;
    LOADROW(r0 - 4, ci, cj, hi, hj);

#pragma unroll 1
    for (int K = 0; K < NK; ++K) {
        // software-pipelined prefetch of row K+1 (RI=-1 on last iter -> zeros)
        float2 ni, nj; float nhi, nhj;
        LOADROW((K + 1 < NK) ? (r0 - 3 + K) : -1, ni, nj, nhi, nhj);

        // ring: read outgoing row (K-9), overwrite with incoming row K.
        // Same lane, same address -> program order suffices.
        float4 oldv = make_float4(0.f, 0.f, 0.f, 0.f);
        float2 oldh = make_float2(0.f, 0.f);
        if (K >= 9) {
            oldv = ring[slot][u];
            if (u < 8) oldh = ringH[slot][u];
        }
        ring[slot][u] = make_float4(ci.x, ci.y, cj.x, cj.y);
        if (u < 8) ringH[slot][u] = make_float2(hi, hj);
        slot = (slot == 8) ? 0 : slot + 1;

        // vertical running 9-row sums: 5 quantities x (2 core + 1 halo) cols
        VI0  += ci.x - oldv.x;             VI1  += ci.y - oldv.y;
        VJ0  += cj.x - oldv.z;             VJ1  += cj.y - oldv.w;
        VII0 += ci.x*ci.x - oldv.x*oldv.x; VII1 += ci.y*ci.y - oldv.y*oldv.y;
        VJJ0 += cj.x*cj.x - oldv.z*oldv.z; VJJ1 += cj.y*cj.y - oldv.w*oldv.w;
        VIJ0 += ci.x*cj.x - oldv.x*oldv.z; VIJ1 += ci.y*cj.y - oldv.y*oldv.w;
        hVI  += hi - oldh.x;               hVJ  += hj - oldh.y;
        hVII += hi*hi - oldh.x*oldh.x;
        hVJJ += hj*hj - oldh.y*oldh.y;
        hVIJ += hi*hj - oldh.x*oldh.y;

        if (K >= 8) {    // emit output row r0 + K - 8 (always in-image)
            *(float2*)&Vbuf[0][4 + l0] = make_float2(VI0,  VI1);
            *(float2*)&Vbuf[1][4 + l0] = make_float2(VJ0,  VJ1);
            *(float2*)&Vbuf[2][4 + l0] = make_float2(VII0, VII1);
            *(float2*)&Vbuf[3][4 + l0] = make_float2(VJJ0, VJJ1);
            *(float2*)&Vbuf[4][4 + l0] = make_float2(VIJ0, VIJ1);
            if (u < 8) {
                Vbuf[0][hx] = hVI;  Vbuf[1][hx] = hVJ;  Vbuf[2][hx] = hVII;
                Vbuf[3][hx] = hVJJ; Vbuf[4][hx] = hVIJ;
            }
            __syncthreads();   // 1-wave workgroup: compiles to a wave fence
            float HI0, HI1, HJ0, HJ1, HA0, HA1, HB0, HB1, HC0, HC1;
            HWIN(0, HI0, HI1);
            HWIN(1, HJ0, HJ1);
            HWIN(2, HA0, HA1);
            HWIN(3, HB0, HB1);
            HWIN(4, HC0, HC1);
            CC1(HI0, HJ0, HA0, HB0, HC0);
            CC1(HI1, HJ1, HA1, HB1, HC1);
            __syncthreads();   // WAR fence before next emit's Vbuf writes
        }

        ci = ni; cj = nj; hi = nhi; hj = nhj;
    }

    // single-wave reduction; lane 0 writes the block partial
    float sum = acc;
#pragma unroll
    for (int off = 32; off > 0; off >>= 1) sum += __shfl_down(sum, off, 64);
    if (u == 0) {
        partial[((size_t)b * NROWSTRIP + s) * NCOLSTRIP + cs] = sum;
    }
}

__global__ __launch_bounds__(256) void ncc_reduce(const float* __restrict__ partial,
                                                  float* __restrict__ out) {
    const int t = threadIdx.x;
    double ssum = 0.0;
    for (int idx = t; idx < NPART; idx += 256) ssum += (double)partial[idx];
#pragma unroll
    for (int off = 32; off > 0; off >>= 1) ssum += __shfl_down(ssum, off, 64);

    __shared__ double wsum[4];
    if ((t & 63) == 0) wsum[t >> 6] = ssum;
    __syncthreads();
    if (t == 0) {
        const double total = wsum[0] + wsum[1] + wsum[2] + wsum[3];
        out[0] = (float)(-total / 8388608.0);  // -mean over 32*512*512
    }
}

extern "C" void kernel_launch(void* const* d_in, const int* in_sizes, int n_in,
                              void* d_out, int out_size, void* d_ws, size_t ws_size,
                              hipStream_t stream) {
    const float* I = (const float*)d_in[0];  // y_true
    const float* J = (const float*)d_in[1];  // y_pred
    float* partial = (float*)d_ws;           // NPART floats
    float* out     = (float*)d_out;

    dim3 grid(NCOLSTRIP, NROWSTRIP, BATCH);
    ncc_main<<<grid, 64, 0, stream>>>(I, J, partial);
    ncc_reduce<<<1, 256, 0, stream>>>(partial, out);
}